// Round 2
// baseline (273.030 us; speedup 1.0000x reference)
//
#include <hip/hip_runtime.h>
#include <hip/hip_bf16.h>
#include <float.h>
#include <limits.h>

#define HH 512
#define WW 512
#define NC 5
#define NBS 4
#define CF 128
#define DD 64
#define NN 2048
#define HW 262144
#define OUT_RW 5242880   /* 4*5*1*512*512 */
#define LN2F 0.6931471805599453f

/* ws layout (bytes) */
#define WS_MODE   0      /* int               */
#define WS_BTV    256    /* float[320*3]      */
#define WS_BTI    4096   /* int[320*3]        */
#define WS_PEAKS  8192   /* int[15*2] (r,c)   */
#define WS_WSOFT  8448   /* float[15]         */
#define WS_RLOSS  12288  /* float[2048]       */
#define WS_RVALID 20480  /* int[2048]         */

#define BETTER(v1,i1,v2,i2) ((v1) > (v2) || ((v1) == (v2) && (i1) < (i2)))

/* ---------- mask dtype detection (int32 / float32 / raw bool bytes) ---------- */
__global__ void k_detect(const unsigned int* __restrict__ nm, int* __restrict__ mode){
  __shared__ int s01[256]; __shared__ int sf[256];
  int tid = threadIdx.x;
  int c01 = 0, cf = 0;
  for (int t = tid; t < 16384; t += 256){
    unsigned int w = nm[t];
    c01 += (w <= 1u);
    cf  += (w == 0u || w == 0x3F800000u);
  }
  s01[tid] = c01; sf[tid] = cf;
  __syncthreads();
  for (int off = 128; off; off >>= 1){
    if (tid < off){ s01[tid] += s01[tid+off]; sf[tid] += sf[tid+off]; }
    __syncthreads();
  }
  if (tid == 0){
    int m = 2;
    if (s01[0] == 16384) m = 0;        /* int32 0/1 */
    else if (sf[0] == 16384) m = 1;    /* float32 0/1 */
    *mode = m;                          /* raw bytes */
  }
}

__device__ __forceinline__ bool read_mask(const void* p, int idx, int mode){
  if (mode == 0) return ((const int*)p)[idx] != 0;
  if (mode == 1) return ((const float*)p)[idx] != 0.0f;
  return ((const unsigned char*)p)[idx] != 0;
}

/* ---------- NMS (5x5 SAME maxpool) + per-stripe top-3, batch 0 only ---------- */
__global__ __launch_bounds__(256) void k_nms(const float* __restrict__ heat,
                                             float* __restrict__ btv, int* __restrict__ bti){
  int bx = blockIdx.x;
  int c = bx >> 6, s = bx & 63;           /* 5 channels x 64 stripes */
  const float* Hc = heat + c * HW;
  int t = threadIdx.x;
  float v0=-FLT_MAX, v1=-FLT_MAX, v2=-FLT_MAX;
  int   i0=INT_MAX,  i1=INT_MAX,  i2=INT_MAX;
  int base = s * 4096;
  for (int p = base + t; p < base + 4096; p += 256){
    int r = p >> 9, col = p & 511;
    float v = Hc[p];
    float m = v;
    #pragma unroll
    for (int dr = -2; dr <= 2; ++dr){
      int rr = r + dr;
      if ((unsigned)rr >= (unsigned)HH) continue;
      const float* Hr = Hc + (rr << 9);
      #pragma unroll
      for (int dc = -2; dc <= 2; ++dc){
        int c2 = col + dc;
        if ((unsigned)c2 >= (unsigned)WW) continue;
        m = fmaxf(m, Hr[c2]);
      }
    }
    float nv = (v == m) ? v : 0.0f;       /* nms = heat * (heat==pool) */
    if (BETTER(nv, p, v2, i2)){
      if (BETTER(nv, p, v0, i0)){ v2=v1;i2=i1; v1=v0;i1=i0; v0=nv;i0=p; }
      else if (BETTER(nv, p, v1, i1)){ v2=v1;i2=i1; v1=nv;i1=p; }
      else { v2=nv; i2=p; }
    }
  }
  __shared__ float sv[256][3];
  __shared__ int   si[256][3];
  sv[t][0]=v0; sv[t][1]=v1; sv[t][2]=v2;
  si[t][0]=i0; si[t][1]=i1; si[t][2]=i2;
  for (int off = 128; off; off >>= 1){
    __syncthreads();
    if (t < off){
      float a0=sv[t][0], a1=sv[t][1], a2=sv[t][2];
      int   ai0=si[t][0], ai1=si[t][1], ai2=si[t][2];
      float b0=sv[t+off][0], b1_=sv[t+off][1], b2_=sv[t+off][2];
      int   bi0=si[t+off][0], bi1=si[t+off][1], bi2=si[t+off][2];
      float x0,x1,x2; int y0,y1,y2;
      if (BETTER(a0,ai0,b0,bi0)){ x0=a0;y0=ai0; a0=a1;ai0=ai1; a1=a2;ai1=ai2; a2=-FLT_MAX; ai2=INT_MAX; }
      else { x0=b0;y0=bi0; b0=b1_;bi0=bi1; b1_=b2_;bi1=bi2; b2_=-FLT_MAX; bi2=INT_MAX; }
      if (BETTER(a0,ai0,b0,bi0)){ x1=a0;y1=ai0; a0=a1;ai0=ai1; }
      else { x1=b0;y1=bi0; b0=b1_;bi0=bi1; }
      if (BETTER(a0,ai0,b0,bi0)){ x2=a0;y2=ai0; }
      else { x2=b0;y2=bi0; }
      sv[t][0]=x0; sv[t][1]=x1; sv[t][2]=x2;
      si[t][0]=y0; si[t][1]=y1; si[t][2]=y2;
    }
  }
  if (t == 0){
    int o = bx * 3;
    btv[o]=sv[0][0]; btv[o+1]=sv[0][1]; btv[o+2]=sv[0][2];
    bti[o]=si[0][0]; bti[o+1]=si[0][1]; bti[o+2]=si[0][2];
  }
}

/* ---------- merge stripe winners -> final top-3 coords per channel ---------- */
__global__ void k_merge(const float* __restrict__ btv, const int* __restrict__ bti,
                        int* __restrict__ peaks){
  if (threadIdx.x != 0) return;
  int c = blockIdx.x;
  float v0=-FLT_MAX,v1=-FLT_MAX,v2=-FLT_MAX; int i0=INT_MAX,i1=INT_MAX,i2=INT_MAX;
  int base = c * 64 * 3;
  for (int e = 0; e < 192; ++e){
    float nv = btv[base+e]; int ni = bti[base+e];
    if (BETTER(nv,ni,v2,i2)){
      if (BETTER(nv,ni,v0,i0)){ v2=v1;i2=i1; v1=v0;i1=i0; v0=nv;i0=ni; }
      else if (BETTER(nv,ni,v1,i1)){ v2=v1;i2=i1; v1=nv;i1=ni; }
      else { v2=nv;i2=ni; }
    }
  }
  peaks[c*6+0]=i0>>9; peaks[c*6+1]=i0&511;
  peaks[c*6+2]=i1>>9; peaks[c*6+3]=i1&511;
  peaks[c*6+4]=i2>>9; peaks[c*6+5]=i2&511;
}

/* ---------- gather + MLP + normalize + logits + softmax(w) ---------- */
__global__ __launch_bounds__(1024) void k_mlp(const float* __restrict__ fm,
                                              const float* __restrict__ W1, const float* __restrict__ b1,
                                              const float* __restrict__ W2, const float* __restrict__ b2,
                                              const float* __restrict__ pemb, const float* __restrict__ lsc,
                                              const int* __restrict__ peaks, float* __restrict__ wsoft,
                                              float* __restrict__ out){
  __shared__ float samp[15][CF];
  __shared__ float hbuf[15][DD];
  __shared__ float logits[15];
  __shared__ int pk[30];
  int tid = threadIdx.x;
  if (tid < 30) pk[tid] = peaks[tid];
  __syncthreads();
  for (int t = tid; t < 15*CF; t += 1024){
    int vk = t >> 7, ch = t & 127;
    int v = vk / 3;
    int r = pk[vk*2], cc = pk[vk*2+1];
    samp[vk][ch] = fm[((v*CF + ch) << 18) + (r << 9) + cc];  /* integer-coord "bilinear" = gather */
  }
  __syncthreads();
  int vk = tid >> 6, d = tid & 63;
  if (vk < 15){
    float acc = b1[d];
    #pragma unroll 4
    for (int ch = 0; ch < CF; ++ch) acc += samp[vk][ch] * W1[ch*DD + d];
    hbuf[vk][d] = fmaxf(acc, 0.0f);
  }
  __syncthreads();
  if (vk < 15){
    float acc = b2[d];
    #pragma unroll 4
    for (int e = 0; e < DD; ++e) acc += hbuf[vk][e] * W2[e*DD + d];
    float ss = acc * acc;
    #pragma unroll
    for (int off = 32; off; off >>= 1) ss += __shfl_xor(ss, off);
    float inv = 1.0f / fmaxf(sqrtf(ss), 1e-12f);
    float contrib = (acc * inv) * pemb[d];
    #pragma unroll
    for (int off = 32; off; off >>= 1) contrib += __shfl_xor(contrib, off);
    if (d == 0){
      float scale = fminf(__expf(lsc[0]), 100.0f);
      logits[vk] = contrib * scale;
    }
  }
  __syncthreads();
  if (tid < 5){
    int v = tid;
    float l0 = logits[v*3], l1 = logits[v*3+1], l2 = logits[v*3+2];
    float mm = fmaxf(l0, fmaxf(l1, l2));
    float e0 = __expf(l0-mm), e1 = __expf(l1-mm), e2 = __expf(l2-mm);
    float s = e0 + e1 + e2;
    wsoft[v*3] = e0/s; wsoft[v*3+1] = e1/s; wsoft[v*3+2] = e2/s;
    out[OUT_RW + v*3 + 0] = l0;
    out[OUT_RW + v*3 + 1] = l1;
    out[OUT_RW + v*3 + 2] = l2;
  }
}

/* ---------- reweighted = heat + sum_k w*gauss  (bias computed once, 4 batches) ---------- */
__global__ __launch_bounds__(256) void k_reweight(const float* __restrict__ heat,
                                                  const int* __restrict__ peaks,
                                                  const float* __restrict__ wsoft,
                                                  float* __restrict__ out){
  __shared__ int pk6[6]; __shared__ float w3[3];
  int gid = blockIdx.x * 256 + threadIdx.x;      /* < 5*262144, one channel per block */
  int c = gid >> 18;
  if (threadIdx.x < 6) pk6[threadIdx.x] = peaks[c*6 + threadIdx.x];
  if (threadIdx.x < 3) w3[threadIdx.x]  = wsoft[c*3 + threadIdx.x];
  __syncthreads();
  int rem = gid & (HW - 1);
  int h = rem >> 9, x = rem & 511;
  float bias = 0.0f;
  #pragma unroll
  for (int k = 0; k < 3; ++k){
    float dr = (float)h - (float)pk6[k*2];
    float dc = (float)x - (float)pk6[k*2+1];
    bias += w3[k] * __expf(-(dr*dr + dc*dc) * (1.0f/18.0f));
  }
  #pragma unroll
  for (int b = 0; b < NBS; ++b){
    int idx = ((b*NC + c) << 18) + rem;
    out[idx] = heat[idx] + bias;
  }
}

/* ---------- contrastive LSE: 8 rows per block, E tiled in padded LDS ---------- */
__device__ __forceinline__ void online_upd(float x, float& m, float& s){
  if (x > m){ s = s * __expf(m - x) + 1.0f; m = x; }
  else      { s += __expf(x - m); }
}
__device__ __forceinline__ void wave_red(float& m, float& s){
  #pragma unroll
  for (int off = 32; off; off >>= 1){
    float om = __shfl_xor(m, off);
    float os = __shfl_xor(s, off);
    if (om > m){ s = s * __expf(m - om) + os; m = om; }
    else       { s = s + os * __expf(om - m); }
  }
}
__global__ __launch_bounds__(256) void k_lse(const float* __restrict__ E,
                                             const void* __restrict__ pm, const void* __restrict__ nmm,
                                             const void* __restrict__ hmm, const int* __restrict__ mode_p,
                                             float* __restrict__ rloss, int* __restrict__ rvalid){
  int mode = *mode_p;
  int i0 = blockIdx.x * 8;
  int tid = threadIdx.x;
  int g = tid >> 6, l = tid & 63;          /* 4 waves x 64 lanes; wave g owns rows i0+2g, i0+2g+1 */
  __shared__ float ei[8][DD];
  __shared__ float tile[64 * 65];
  for (int t = tid; t < 8*DD; t += 256) ei[t>>6][t&63] = E[(i0 + (t>>6))*DD + (t&63)];
  int ra = i0 + g*2, rb = ra + 1;
  float mpa=-FLT_MAX, spa=0.f, mna=-FLT_MAX, sna=0.f;
  float mpb=-FLT_MAX, spb=0.f, mnb=-FLT_MAX, snb=0.f;
  for (int t0 = 0; t0 < NN; t0 += 64){
    __syncthreads();
    for (int e = tid; e < 64*DD; e += 256){
      int r = e >> 6, d = e & 63;
      tile[r*65 + d] = E[(t0 + r)*DD + d];
    }
    __syncthreads();
    int j = t0 + l;
    float da = 0.f, db = 0.f;
    #pragma unroll 8
    for (int d = 0; d < DD; ++d){
      float x = tile[l*65 + d];
      da += ei[g*2][d]   * x;
      db += ei[g*2+1][d] * x;
    }
    da /= 0.07f; db /= 0.07f;
    {
      int idx = ra*NN + j;
      bool p = read_mask(pm, idx, mode);
      bool n = read_mask(nmm, idx, mode);
      bool hd = read_mask(hmm, idx, mode);
      float xp = p ? da : -1e9f;
      float xn = (n ? da : -1e9f) + (hd ? LN2F : 0.f);
      online_upd(xp, mpa, spa);
      online_upd(xn, mna, sna);
    }
    {
      int idx = rb*NN + j;
      bool p = read_mask(pm, idx, mode);
      bool n = read_mask(nmm, idx, mode);
      bool hd = read_mask(hmm, idx, mode);
      float xp = p ? db : -1e9f;
      float xn = (n ? db : -1e9f) + (hd ? LN2F : 0.f);
      online_upd(xp, mpb, spb);
      online_upd(xn, mnb, snb);
    }
  }
  wave_red(mpa, spa); wave_red(mna, sna);
  wave_red(mpb, spb); wave_red(mnb, snb);
  if (l == 0){
    {
      float lp = mpa + __logf(spa), ln = mna + __logf(sna);
      float mm = fmaxf(lp, ln);
      float ld = mm + __logf(__expf(lp-mm) + __expf(ln-mm));
      bool valid = mpa > -1e8f;
      rloss[ra]  = valid ? (ld - lp) : 0.f;
      rvalid[ra] = valid ? 1 : 0;
    }
    {
      float lp = mpb + __logf(spb), ln = mnb + __logf(snb);
      float mm = fmaxf(lp, ln);
      float ld = mm + __logf(__expf(lp-mm) + __expf(ln-mm));
      bool valid = mpb > -1e8f;
      rloss[rb]  = valid ? (ld - lp) : 0.f;
      rvalid[rb] = valid ? 1 : 0;
    }
  }
}

/* ---------- c_loss reduce + cons_loss ---------- */
__global__ __launch_bounds__(256) void k_final(const float* __restrict__ rloss, const int* __restrict__ rvalid,
                                               const float* __restrict__ E, const float* __restrict__ T,
                                               float* __restrict__ out){
  int tid = threadIdx.x;
  float s = 0.f; int cnt = 0;
  for (int i = tid; i < NN; i += 256){ s += rloss[i]; cnt += rvalid[i]; }
  float cs = 0.f;
  for (int p = tid; p < NN-1; p += 256){
    float dot = 0.f, na = 0.f, nb = 0.f;
    #pragma unroll 8
    for (int d = 0; d < DD; ++d){
      float a = E[p*DD + d], b = E[(p+1)*DD + d];
      dot += a*b; na += a*a; nb += b*b;
    }
    float cosv = dot / fmaxf(sqrtf(na) * sqrtf(nb), 1e-8f);
    float t0 = T[p*3]   - T[p*3+3];
    float t1 = T[p*3+1] - T[p*3+4];
    float t2 = T[p*3+2] - T[p*3+5];
    float td = sqrtf(t0*t0 + t1*t1 + t2*t2);
    if (td < 0.1f) cs += fmaxf(0.9f - cosv, 0.f);
  }
  __shared__ float r1[256]; __shared__ int r2[256]; __shared__ float r3[256];
  r1[tid] = s; r2[tid] = cnt; r3[tid] = cs;
  __syncthreads();
  for (int off = 128; off; off >>= 1){
    if (tid < off){ r1[tid] += r1[tid+off]; r2[tid] += r2[tid+off]; r3[tid] += r3[tid+off]; }
    __syncthreads();
  }
  if (tid == 0){
    int c = r2[0] > 1 ? r2[0] : 1;
    out[OUT_RW + 15] = r1[0] / (float)c;
    out[OUT_RW + 16] = r3[0] / (float)(NN-1);
  }
}

extern "C" void kernel_launch(void* const* d_in, const int* in_sizes, int n_in,
                              void* d_out, int out_size, void* d_ws, size_t ws_size,
                              hipStream_t stream) {
  (void)in_sizes; (void)n_in; (void)out_size; (void)ws_size;
  const float* heat = (const float*)d_in[0];
  const float* fm   = (const float*)d_in[1];
  const float* pemb = (const float*)d_in[2];
  const float* W1   = (const float*)d_in[3];
  const float* b1   = (const float*)d_in[4];
  const float* W2   = (const float*)d_in[5];
  const float* b2   = (const float*)d_in[6];
  const float* lsc  = (const float*)d_in[7];
  const float* E    = (const float*)d_in[8];
  const float* T    = (const float*)d_in[9];
  const void*  pm   = d_in[10];
  const void*  nmm  = d_in[11];
  const void*  hmm  = d_in[12];
  float* out = (float*)d_out;
  char* ws = (char*)d_ws;
  int*   mode   = (int*)(ws + WS_MODE);
  float* btv    = (float*)(ws + WS_BTV);
  int*   bti    = (int*)(ws + WS_BTI);
  int*   peaks  = (int*)(ws + WS_PEAKS);
  float* wsoft  = (float*)(ws + WS_WSOFT);
  float* rloss  = (float*)(ws + WS_RLOSS);
  int*   rvalid = (int*)(ws + WS_RVALID);

  hipLaunchKernelGGL(k_detect,   dim3(1),    dim3(256),  0, stream, (const unsigned int*)nmm, mode);
  hipLaunchKernelGGL(k_nms,      dim3(320),  dim3(256),  0, stream, heat, btv, bti);
  hipLaunchKernelGGL(k_merge,    dim3(5),    dim3(64),   0, stream, btv, bti, peaks);
  hipLaunchKernelGGL(k_mlp,      dim3(1),    dim3(1024), 0, stream, fm, W1, b1, W2, b2, pemb, lsc, peaks, wsoft, out);
  hipLaunchKernelGGL(k_reweight, dim3(5120), dim3(256),  0, stream, heat, peaks, wsoft, out);
  hipLaunchKernelGGL(k_lse,      dim3(256),  dim3(256),  0, stream, E, pm, nmm, hmm, mode, rloss, rvalid);
  hipLaunchKernelGGL(k_final,    dim3(1),    dim3(256),  0, stream, rloss, rvalid, E, T, out);
}

// Round 3
// 146.901 us; speedup vs baseline: 1.8586x; 1.8586x over previous
//
#include <hip/hip_runtime.h>
#include <float.h>
#include <limits.h>

typedef float4 f4;

#define HH 512
#define WW 512
#define NC 5
#define NBS 4
#define CF 128
#define DD 64
#define NN 2048
#define HW 262144
#define OUT_RW 5242880   /* 4*5*1*512*512 */
#define LN2F 0.6931471805599453f
#define INV_TEMP 14.285714285714286f

/* ws layout (bytes) */
#define WS_MODE   0        /* int                 */
#define WS_PEAKS  64       /* int[30]             */
#define WS_WSOFT  192      /* float[15]           */
#define WS_BTV    256      /* float[1280*3]       */
#define WS_BTI    15616    /* int[1280*3]         */
#define WS_RLOSS  31232    /* float[2048]         */
#define WS_RVALID 39424    /* int[2048]           */
#define WS_CONS   47616    /* float[8]            */
#define WS_PMM    49152    /* float[32*2048] x4   */
#define WS_PMS    (WS_PMM + 262144)
#define WS_NMM    (WS_PMS + 262144)
#define WS_NMS    (WS_NMM + 262144)

#define BETTER(v1,i1,v2,i2) ((v1) > (v2) || ((v1) == (v2) && (i1) < (i2)))
#define DOT4(a,b) ((a).x*(b).x + (a).y*(b).y + (a).z*(b).z + (a).w*(b).w)

/* ---------- mask dtype detection (int32 / float32 / raw bool bytes) ---------- */
__global__ void k_detect(const unsigned int* __restrict__ nm, int* __restrict__ mode){
  __shared__ int s01[256]; __shared__ int sf[256];
  int tid = threadIdx.x;
  int c01 = 0, cf = 0;
  for (int t = tid; t < 4096; t += 256){
    unsigned int w = nm[t];
    c01 += (w <= 1u);
    cf  += (w == 0u || w == 0x3F800000u);
  }
  s01[tid] = c01; sf[tid] = cf;
  __syncthreads();
  for (int off = 128; off; off >>= 1){
    if (tid < off){ s01[tid] += s01[tid+off]; sf[tid] += sf[tid+off]; }
    __syncthreads();
  }
  if (tid == 0){
    int m = 2;
    if (s01[0] == 4096) m = 0;         /* int32 0/1 */
    else if (sf[0] == 4096) m = 1;     /* float32 0/1 */
    *mode = m;                          /* else raw bytes */
  }
}

/* ---------- NMS (5x5 SAME maxpool) + per-stripe top-3, batch 0 only ---------- */
__global__ __launch_bounds__(256) void k_nms(const float* __restrict__ heat,
                                             float* __restrict__ btv, int* __restrict__ bti){
  int bx = blockIdx.x;
  int c = bx >> 8, s = bx & 255;          /* 5 channels x 256 stripes of 1024 px */
  const float* Hc = heat + c * HW;
  int t = threadIdx.x;
  float v0=-FLT_MAX, v1=-FLT_MAX, v2=-FLT_MAX;
  int   i0=INT_MAX,  i1=INT_MAX,  i2=INT_MAX;
  int base = s * 1024;
  #pragma unroll
  for (int k = 0; k < 4; ++k){
    int p = base + t + 256*k;
    int r = p >> 9, col = p & 511;
    float v = Hc[p];
    float m = v;
    #pragma unroll
    for (int dr = -2; dr <= 2; ++dr){
      int rr = r + dr;
      if ((unsigned)rr >= (unsigned)HH) continue;
      const float* Hr = Hc + (rr << 9);
      #pragma unroll
      for (int dc = -2; dc <= 2; ++dc){
        int c2 = col + dc;
        if ((unsigned)c2 >= (unsigned)WW) continue;
        m = fmaxf(m, Hr[c2]);
      }
    }
    float nv = (v == m) ? v : 0.0f;       /* nms = heat * (heat==pool) */
    if (BETTER(nv, p, v2, i2)){
      if (BETTER(nv, p, v0, i0)){ v2=v1;i2=i1; v1=v0;i1=i0; v0=nv;i0=p; }
      else if (BETTER(nv, p, v1, i1)){ v2=v1;i2=i1; v1=nv;i1=p; }
      else { v2=nv; i2=p; }
    }
  }
  __shared__ float sv[256][3];
  __shared__ int   si[256][3];
  sv[t][0]=v0; sv[t][1]=v1; sv[t][2]=v2;
  si[t][0]=i0; si[t][1]=i1; si[t][2]=i2;
  for (int off = 128; off; off >>= 1){
    __syncthreads();
    if (t < off){
      float a0=sv[t][0], a1=sv[t][1], a2=sv[t][2];
      int   ai0=si[t][0], ai1=si[t][1], ai2=si[t][2];
      float b0=sv[t+off][0], b1_=sv[t+off][1], b2_=sv[t+off][2];
      int   bi0=si[t+off][0], bi1=si[t+off][1], bi2=si[t+off][2];
      float x0,x1,x2; int y0,y1,y2;
      if (BETTER(a0,ai0,b0,bi0)){ x0=a0;y0=ai0; a0=a1;ai0=ai1; a1=a2;ai1=ai2; a2=-FLT_MAX; ai2=INT_MAX; }
      else { x0=b0;y0=bi0; b0=b1_;bi0=bi1; b1_=b2_;bi1=bi2; b2_=-FLT_MAX; bi2=INT_MAX; }
      if (BETTER(a0,ai0,b0,bi0)){ x1=a0;y1=ai0; a0=a1;ai0=ai1; }
      else { x1=b0;y1=bi0; b0=b1_;bi0=bi1; }
      if (BETTER(a0,ai0,b0,bi0)){ x2=a0;y2=ai0; }
      else { x2=b0;y2=bi0; }
      sv[t][0]=x0; sv[t][1]=x1; sv[t][2]=x2;
      si[t][0]=y0; si[t][1]=y1; si[t][2]=y2;
    }
  }
  if (t == 0){
    int o = bx * 3;
    btv[o]=sv[0][0]; btv[o+1]=sv[0][1]; btv[o+2]=sv[0][2];
    bti[o]=si[0][0]; bti[o+1]=si[0][1]; bti[o+2]=si[0][2];
  }
}

/* ---------- merge stripe winners -> final top-3 coords per channel ---------- */
__global__ __launch_bounds__(256) void k_merge(const float* __restrict__ btv, const int* __restrict__ bti,
                                               int* __restrict__ peaks){
  int c = blockIdx.x;
  int t = threadIdx.x;
  int e0 = c*768 + t*3;
  float v0 = btv[e0], v1 = btv[e0+1], v2 = btv[e0+2];
  int   i0 = bti[e0], i1 = bti[e0+1], i2 = bti[e0+2];   /* already sorted per stripe */
  __shared__ float sv[256][3];
  __shared__ int   si[256][3];
  sv[t][0]=v0; sv[t][1]=v1; sv[t][2]=v2;
  si[t][0]=i0; si[t][1]=i1; si[t][2]=i2;
  for (int off = 128; off; off >>= 1){
    __syncthreads();
    if (t < off){
      float a0=sv[t][0], a1=sv[t][1], a2=sv[t][2];
      int   ai0=si[t][0], ai1=si[t][1], ai2=si[t][2];
      float b0=sv[t+off][0], b1_=sv[t+off][1], b2_=sv[t+off][2];
      int   bi0=si[t+off][0], bi1=si[t+off][1], bi2=si[t+off][2];
      float x0,x1,x2; int y0,y1,y2;
      if (BETTER(a0,ai0,b0,bi0)){ x0=a0;y0=ai0; a0=a1;ai0=ai1; a1=a2;ai1=ai2; a2=-FLT_MAX; ai2=INT_MAX; }
      else { x0=b0;y0=bi0; b0=b1_;bi0=bi1; b1_=b2_;bi1=bi2; b2_=-FLT_MAX; bi2=INT_MAX; }
      if (BETTER(a0,ai0,b0,bi0)){ x1=a0;y1=ai0; a0=a1;ai0=ai1; }
      else { x1=b0;y1=bi0; b0=b1_;bi0=bi1; }
      if (BETTER(a0,ai0,b0,bi0)){ x2=a0;y2=ai0; }
      else { x2=b0;y2=bi0; }
      sv[t][0]=x0; sv[t][1]=x1; sv[t][2]=x2;
      si[t][0]=y0; si[t][1]=y1; si[t][2]=y2;
    }
  }
  if (t == 0){
    peaks[c*6+0]=si[0][0]>>9; peaks[c*6+1]=si[0][0]&511;
    peaks[c*6+2]=si[0][1]>>9; peaks[c*6+3]=si[0][1]&511;
    peaks[c*6+4]=si[0][2]>>9; peaks[c*6+5]=si[0][2]&511;
  }
}

/* ---------- gather + MLP + normalize + logits + softmax(w) ---------- */
__global__ __launch_bounds__(1024) void k_mlp(const float* __restrict__ fm,
                                              const float* __restrict__ W1, const float* __restrict__ b1,
                                              const float* __restrict__ W2, const float* __restrict__ b2,
                                              const float* __restrict__ pemb, const float* __restrict__ lsc,
                                              const int* __restrict__ peaks, float* __restrict__ wsoft,
                                              float* __restrict__ out){
  __shared__ float samp[15][CF];
  __shared__ float hbuf[15][DD];
  __shared__ float logits[15];
  __shared__ int pk[30];
  int tid = threadIdx.x;
  if (tid < 30) pk[tid] = peaks[tid];
  __syncthreads();
  for (int t = tid; t < 15*CF; t += 1024){
    int vk = t >> 7, ch = t & 127;
    int v = vk / 3;
    int r = pk[vk*2], cc = pk[vk*2+1];
    samp[vk][ch] = fm[((v*CF + ch) << 18) + (r << 9) + cc];  /* integer-coord bilinear = gather */
  }
  __syncthreads();
  int vk = tid >> 6, d = tid & 63;
  if (vk < 15){
    float acc = b1[d];
    #pragma unroll 4
    for (int ch = 0; ch < CF; ++ch) acc += samp[vk][ch] * W1[ch*DD + d];
    hbuf[vk][d] = fmaxf(acc, 0.0f);
  }
  __syncthreads();
  if (vk < 15){
    float acc = b2[d];
    #pragma unroll 4
    for (int e = 0; e < DD; ++e) acc += hbuf[vk][e] * W2[e*DD + d];
    float ss = acc * acc;
    #pragma unroll
    for (int off = 32; off; off >>= 1) ss += __shfl_xor(ss, off);
    float inv = 1.0f / fmaxf(sqrtf(ss), 1e-12f);
    float contrib = (acc * inv) * pemb[d];
    #pragma unroll
    for (int off = 32; off; off >>= 1) contrib += __shfl_xor(contrib, off);
    if (d == 0){
      float scale = fminf(__expf(lsc[0]), 100.0f);
      logits[vk] = contrib * scale;
    }
  }
  __syncthreads();
  if (tid < 5){
    int v = tid;
    float l0 = logits[v*3], l1 = logits[v*3+1], l2 = logits[v*3+2];
    float mm = fmaxf(l0, fmaxf(l1, l2));
    float e0 = __expf(l0-mm), e1 = __expf(l1-mm), e2 = __expf(l2-mm);
    float s = e0 + e1 + e2;
    wsoft[v*3] = e0/s; wsoft[v*3+1] = e1/s; wsoft[v*3+2] = e2/s;
    out[OUT_RW + v*3 + 0] = l0;
    out[OUT_RW + v*3 + 1] = l1;
    out[OUT_RW + v*3 + 2] = l2;
  }
}

/* ---------- reweighted = heat + sum_k w*gauss (float4, exp-skip far pixels) ---------- */
__global__ __launch_bounds__(256) void k_reweight(const float* __restrict__ heat,
                                                  const int* __restrict__ peaks,
                                                  const float* __restrict__ wsoft,
                                                  float* __restrict__ out){
  __shared__ float pr[3], pc[3], w3[3];
  int t = threadIdx.x;
  int gid = blockIdx.x * 256 + t;          /* 0..327679, 4 px each */
  int c = gid >> 16;
  if (t < 3){
    pr[t] = (float)peaks[c*6 + t*2];
    pc[t] = (float)peaks[c*6 + t*2 + 1];
    w3[t] = wsoft[c*3 + t];
  }
  __syncthreads();
  int rem = (gid & 65535) << 2;
  int h = rem >> 9, x0 = rem & 511;
  float bias0=0.f, bias1=0.f, bias2=0.f, bias3=0.f;
  #pragma unroll
  for (int k = 0; k < 3; ++k){
    float dr = (float)h - pr[k];
    float dr2 = dr*dr;
    float w = w3[k];
    float d0 = (float)x0     - pc[k];
    float d1 = (float)(x0+1) - pc[k];
    float d2 = (float)(x0+2) - pc[k];
    float d3 = (float)(x0+3) - pc[k];
    float q0 = dr2 + d0*d0, q1 = dr2 + d1*d1, q2 = dr2 + d2*d2, q3 = dr2 + d3*d3;
    if (q0 < 324.f) bias0 += w * __expf(-q0 * (1.0f/18.0f));
    if (q1 < 324.f) bias1 += w * __expf(-q1 * (1.0f/18.0f));
    if (q2 < 324.f) bias2 += w * __expf(-q2 * (1.0f/18.0f));
    if (q3 < 324.f) bias3 += w * __expf(-q3 * (1.0f/18.0f));
  }
  #pragma unroll
  for (int b = 0; b < NBS; ++b){
    int idx = ((b*NC + c) << 18) + rem;
    f4 hv = *(const f4*)(heat + idx);
    f4 o; o.x = hv.x + bias0; o.y = hv.y + bias1; o.z = hv.z + bias2; o.w = hv.w + bias3;
    *(f4*)(out + idx) = o;
  }
}

/* ---------- online-softmax helpers ---------- */
__device__ __forceinline__ void online_upd(float x, float& m, float& s){
  if (x > m){ s = s * __expf(m - x) + 1.0f; m = x; }
  else      { s += __expf(x - m); }
}
__device__ __forceinline__ void comb(float& m, float& s, float om, float os){
  if (om > m){ s = s * __expf(m - om) + os; m = om; }
  else       { s = s + os * __expf(om - m); }
}

/* ---------- sim = E@E^T tiled 64x64, fused mask + partial online-LSE ---------- */
__global__ __launch_bounds__(256) void k_sim(const float* __restrict__ E,
    const void* __restrict__ pm, const void* __restrict__ nm, const void* __restrict__ hm,
    const int* __restrict__ mode_p,
    float* __restrict__ pmm, float* __restrict__ pms,
    float* __restrict__ nmm_, float* __restrict__ nms_){
  int mode = *mode_p;
  int b = blockIdx.x;
  int bc = b & 31, br = b >> 5;
  int R0 = br * 64, C0 = bc * 64;
  int t = threadIdx.x;
  __shared__ f4 As[64*17];   /* A[row][dc] at row*17+dc  (pad -> 2-way max) */
  __shared__ f4 Bs[64*16];   /* B[col][dc] at col*16 + (dc ^ (col>>2))      */
  const f4* E4 = (const f4*)E;
  #pragma unroll
  for (int k = 0; k < 4; ++k){
    int f = t + 256*k;                  /* 0..1023 */
    int rr = f >> 4, dc = f & 15;
    As[rr*17 + dc] = E4[(R0 + rr)*16 + dc];
    Bs[rr*16 + (dc ^ ((rr >> 2) & 15))] = E4[(C0 + rr)*16 + dc];
  }
  __syncthreads();
  int tx = t & 15, ty = t >> 4;
  float acc[4][4];
  #pragma unroll
  for (int i = 0; i < 4; ++i)
    #pragma unroll
    for (int j = 0; j < 4; ++j) acc[i][j] = 0.f;
  #pragma unroll
  for (int dc = 0; dc < 16; ++dc){
    f4 a0 = As[(ty*4+0)*17 + dc];
    f4 a1 = As[(ty*4+1)*17 + dc];
    f4 a2 = As[(ty*4+2)*17 + dc];
    f4 a3 = As[(ty*4+3)*17 + dc];
    int sw = dc ^ tx;
    f4 b0 = Bs[(tx*4+0)*16 + sw];
    f4 b1 = Bs[(tx*4+1)*16 + sw];
    f4 b2 = Bs[(tx*4+2)*16 + sw];
    f4 b3 = Bs[(tx*4+3)*16 + sw];
    acc[0][0] += DOT4(a0,b0); acc[0][1] += DOT4(a0,b1); acc[0][2] += DOT4(a0,b2); acc[0][3] += DOT4(a0,b3);
    acc[1][0] += DOT4(a1,b0); acc[1][1] += DOT4(a1,b1); acc[1][2] += DOT4(a1,b2); acc[1][3] += DOT4(a1,b3);
    acc[2][0] += DOT4(a2,b0); acc[2][1] += DOT4(a2,b1); acc[2][2] += DOT4(a2,b2); acc[2][3] += DOT4(a2,b3);
    acc[3][0] += DOT4(a3,b0); acc[3][1] += DOT4(a3,b1); acc[3][2] += DOT4(a3,b2); acc[3][3] += DOT4(a3,b3);
  }
  int rbase = R0 + ty*4;
  int cbase = C0 + tx*4;
  #pragma unroll
  for (int ri = 0; ri < 4; ++ri){
    int row = rbase + ri;
    int ofs = row * NN + cbase;
    bool p0,p1,p2,p3, n0,n1,n2,n3, h0,h1,h2,h3;
    if (mode == 0){
      int4 a = *(const int4*)((const int*)pm + ofs);
      int4 bq = *(const int4*)((const int*)nm + ofs);
      int4 cq = *(const int4*)((const int*)hm + ofs);
      p0=a.x!=0; p1=a.y!=0; p2=a.z!=0; p3=a.w!=0;
      n0=bq.x!=0; n1=bq.y!=0; n2=bq.z!=0; n3=bq.w!=0;
      h0=cq.x!=0; h1=cq.y!=0; h2=cq.z!=0; h3=cq.w!=0;
    } else if (mode == 1){
      f4 a = *(const f4*)((const float*)pm + ofs);
      f4 bq = *(const f4*)((const float*)nm + ofs);
      f4 cq = *(const f4*)((const float*)hm + ofs);
      p0=a.x!=0.f; p1=a.y!=0.f; p2=a.z!=0.f; p3=a.w!=0.f;
      n0=bq.x!=0.f; n1=bq.y!=0.f; n2=bq.z!=0.f; n3=bq.w!=0.f;
      h0=cq.x!=0.f; h1=cq.y!=0.f; h2=cq.z!=0.f; h3=cq.w!=0.f;
    } else {
      unsigned int a = *(const unsigned int*)((const unsigned char*)pm + ofs);
      unsigned int bq = *(const unsigned int*)((const unsigned char*)nm + ofs);
      unsigned int cq = *(const unsigned int*)((const unsigned char*)hm + ofs);
      p0=(a&0xffu)!=0; p1=(a&0xff00u)!=0; p2=(a&0xff0000u)!=0; p3=(a&0xff000000u)!=0;
      n0=(bq&0xffu)!=0; n1=(bq&0xff00u)!=0; n2=(bq&0xff0000u)!=0; n3=(bq&0xff000000u)!=0;
      h0=(cq&0xffu)!=0; h1=(cq&0xff00u)!=0; h2=(cq&0xff0000u)!=0; h3=(cq&0xff000000u)!=0;
    }
    float mp=-FLT_MAX, sp=0.f, mn=-FLT_MAX, sn=0.f;
    {
      float s0 = acc[ri][0]*INV_TEMP, s1 = acc[ri][1]*INV_TEMP,
            s2 = acc[ri][2]*INV_TEMP, s3 = acc[ri][3]*INV_TEMP;
      online_upd(p0 ? s0 : -1e9f, mp, sp);
      online_upd(p1 ? s1 : -1e9f, mp, sp);
      online_upd(p2 ? s2 : -1e9f, mp, sp);
      online_upd(p3 ? s3 : -1e9f, mp, sp);
      online_upd((n0 ? s0 : -1e9f) + (h0 ? LN2F : 0.f), mn, sn);
      online_upd((n1 ? s1 : -1e9f) + (h1 ? LN2F : 0.f), mn, sn);
      online_upd((n2 ? s2 : -1e9f) + (h2 ? LN2F : 0.f), mn, sn);
      online_upd((n3 ? s3 : -1e9f) + (h3 ? LN2F : 0.f), mn, sn);
    }
    #pragma unroll
    for (int off = 1; off < 16; off <<= 1){
      float om = __shfl_xor(mp, off), os = __shfl_xor(sp, off);
      comb(mp, sp, om, os);
      om = __shfl_xor(mn, off); os = __shfl_xor(sn, off);
      comb(mn, sn, om, os);
    }
    if (tx == 0){
      pmm [bc*NN + row] = mp;  pms [bc*NN + row] = sp;
      nmm_[bc*NN + row] = mn;  nms_[bc*NN + row] = sn;
    }
  }
}

/* ---------- merge col-block partials -> per-row loss; fused cons pair ---------- */
__global__ __launch_bounds__(256) void k_merge2(const float* __restrict__ pmm, const float* __restrict__ pms,
    const float* __restrict__ nmm_, const float* __restrict__ nms_,
    const float* __restrict__ E, const float* __restrict__ T,
    float* __restrict__ rloss, int* __restrict__ rvalid, float* __restrict__ consp){
  int r = blockIdx.x * 256 + threadIdx.x;
  float mp = pmm[r], sp = pms[r];
  float mn = nmm_[r], sn = nms_[r];
  #pragma unroll 4
  for (int k = 1; k < 32; ++k){
    comb(mp, sp, pmm[k*NN + r], pms[k*NN + r]);
    comb(mn, sn, nmm_[k*NN + r], nms_[k*NN + r]);
  }
  float lp = mp + __logf(sp), ln = mn + __logf(sn);
  float mm = fmaxf(lp, ln);
  float ld = mm + __logf(__expf(lp - mm) + __expf(ln - mm));
  bool valid = mp > -1e8f;
  rloss[r]  = valid ? (ld - lp) : 0.f;
  rvalid[r] = valid ? 1 : 0;
  float cs = 0.f;
  if (r < NN - 1){
    const f4* a4 = (const f4*)(E + r*DD);
    const f4* b4 = (const f4*)(E + (r+1)*DD);
    float dot=0.f, na=0.f, nb=0.f;
    #pragma unroll
    for (int q = 0; q < 16; ++q){
      f4 a = a4[q], b = b4[q];
      dot += DOT4(a,b); na += DOT4(a,a); nb += DOT4(b,b);
    }
    float cosv = dot / fmaxf(sqrtf(na)*sqrtf(nb), 1e-8f);
    float t0 = T[r*3]   - T[r*3+3];
    float t1 = T[r*3+1] - T[r*3+4];
    float t2 = T[r*3+2] - T[r*3+5];
    float td = sqrtf(t0*t0 + t1*t1 + t2*t2);
    if (td < 0.1f) cs = fmaxf(0.9f - cosv, 0.f);
  }
  __shared__ float red[256];
  red[threadIdx.x] = cs;
  __syncthreads();
  for (int off = 128; off; off >>= 1){
    if (threadIdx.x < off) red[threadIdx.x] += red[threadIdx.x + off];
    __syncthreads();
  }
  if (threadIdx.x == 0) consp[blockIdx.x] = red[0];
}

/* ---------- final scalar reduce ---------- */
__global__ __launch_bounds__(256) void k_fin(const float* __restrict__ rloss, const int* __restrict__ rvalid,
                                             const float* __restrict__ consp, float* __restrict__ out){
  int t = threadIdx.x;
  float s = 0.f; int cnt = 0;
  #pragma unroll
  for (int i = t; i < NN; i += 256){ s += rloss[i]; cnt += rvalid[i]; }
  float cs = (t < 8) ? consp[t] : 0.f;
  __shared__ float r1[256]; __shared__ int r2[256]; __shared__ float r3[256];
  r1[t] = s; r2[t] = cnt; r3[t] = cs;
  __syncthreads();
  for (int off = 128; off; off >>= 1){
    if (t < off){ r1[t] += r1[t+off]; r2[t] += r2[t+off]; r3[t] += r3[t+off]; }
    __syncthreads();
  }
  if (t == 0){
    int c = r2[0] > 1 ? r2[0] : 1;
    out[OUT_RW + 15] = r1[0] / (float)c;
    out[OUT_RW + 16] = r3[0] / (float)(NN - 1);
  }
}

extern "C" void kernel_launch(void* const* d_in, const int* in_sizes, int n_in,
                              void* d_out, int out_size, void* d_ws, size_t ws_size,
                              hipStream_t stream) {
  (void)in_sizes; (void)n_in; (void)out_size; (void)ws_size;
  const float* heat = (const float*)d_in[0];
  const float* fm   = (const float*)d_in[1];
  const float* pemb = (const float*)d_in[2];
  const float* W1   = (const float*)d_in[3];
  const float* b1   = (const float*)d_in[4];
  const float* W2   = (const float*)d_in[5];
  const float* b2   = (const float*)d_in[6];
  const float* lsc  = (const float*)d_in[7];
  const float* E    = (const float*)d_in[8];
  const float* T    = (const float*)d_in[9];
  const void*  pm   = d_in[10];
  const void*  nmm  = d_in[11];
  const void*  hmm  = d_in[12];
  float* out = (float*)d_out;
  char* ws = (char*)d_ws;
  int*   mode   = (int*)(ws + WS_MODE);
  int*   peaks  = (int*)(ws + WS_PEAKS);
  float* wsoft  = (float*)(ws + WS_WSOFT);
  float* btv    = (float*)(ws + WS_BTV);
  int*   bti    = (int*)(ws + WS_BTI);
  float* rloss  = (float*)(ws + WS_RLOSS);
  int*   rvalid = (int*)(ws + WS_RVALID);
  float* consp  = (float*)(ws + WS_CONS);
  float* pmm    = (float*)(ws + WS_PMM);
  float* pms    = (float*)(ws + WS_PMS);
  float* nmm2   = (float*)(ws + WS_NMM);
  float* nms2   = (float*)(ws + WS_NMS);

  hipLaunchKernelGGL(k_detect,   dim3(1),    dim3(256),  0, stream, (const unsigned int*)nmm, mode);
  hipLaunchKernelGGL(k_nms,      dim3(1280), dim3(256),  0, stream, heat, btv, bti);
  hipLaunchKernelGGL(k_merge,    dim3(5),    dim3(256),  0, stream, btv, bti, peaks);
  hipLaunchKernelGGL(k_mlp,      dim3(1),    dim3(1024), 0, stream, fm, W1, b1, W2, b2, pemb, lsc, peaks, wsoft, out);
  hipLaunchKernelGGL(k_reweight, dim3(1280), dim3(256),  0, stream, heat, peaks, wsoft, out);
  hipLaunchKernelGGL(k_sim,      dim3(1024), dim3(256),  0, stream, E, pm, nmm, hmm, mode, pmm, pms, nmm2, nms2);
  hipLaunchKernelGGL(k_merge2,   dim3(8),    dim3(256),  0, stream, pmm, pms, nmm2, nms2, E, T, rloss, rvalid, consp);
  hipLaunchKernelGGL(k_fin,      dim3(1),    dim3(256),  0, stream, rloss, rvalid, consp, out);
}